// Round 15
// baseline (143.342 us; speedup 1.0000x reference)
//
#include <hip/hip_runtime.h>
#include <hip/hip_bf16.h>

// Shapes: N=128, C_IN=C_OUT=64, T=128, V=25, S=3, R=8
// ws layout (bytes) — all matrices fp8 e4m3:
//   adjfrag [3][128][64 o][2 ut][64 lane][8 j]   @ 0           25,165,824
//   w3frag  [3][2 kb][4 ot][64 lane][8 j]        @ 25,165,824      12,288
//   xT      [128][3200 tv][64 c]                 @ 25,178,112  26,214,400
//   y8      [128][64][128 t][25 u]               @ 51,392,512  26,214,400
//   xbarp f32 [8 tc][128 n][1600]                @ 77,606,912   6,553,600
//   partials f32 [64 o][2 stat][128 n]           @ 84,160,512      65,536
//   coef f32 [64][2]                             @ 84,226,048         512
//
// NOTE (toolchain, r8/r9): __launch_bounds__ 2nd arg acts as min BLOCKS/CU on
// this hipcc: (512,4)->64 VGPR cap, (512,6)->40, (512,2)->128.
// NOTE (r11): hipLaunchCooperativeKernel breaks under graph capture — avoid.
// NOTE (r12/r13/r14): 3-barrier vs 1-barrier schedules tie; EPI-free phase-0
// costs the same as full k_main -> k_main is dependency-latency-bound.

typedef __attribute__((ext_vector_type(4))) float f32x4;
typedef __attribute__((ext_vector_type(2))) float f32x2;
typedef long long i64;

#define ADJ8_OFF  0
#define W3F8_OFF  25165824
#define XT8_OFF   25178112
#define Y8_OFF    51392512
#define XBARP_OFF 77606912
#define PART_OFF  84160512
#define COEF_OFF  84226048

__device__ inline unsigned short f2bf(float f) {
    union { float f; unsigned int u; } x; x.f = f;
    unsigned int u = x.u;
    return (unsigned short)((u + 0x7FFFu + ((u >> 16) & 1u)) >> 16);
}

// ---- W3 -> B-fragment-linear fp8 ----
__global__ void k_w3prep(const float* __restrict__ W3, unsigned char* __restrict__ w3f) {
    int g = blockIdx.x * 512 + threadIdx.x;          // 0..1535
    if (g >= 1536) return;
    int grp = g >> 6, lane = g & 63;
    int s = grp >> 3, kb = (grp >> 2) & 1, ot = grp & 3;
    int o = ot * 16 + (lane & 15);
    int c0 = kb * 32 + (lane >> 4) * 8;
    const float* src = W3 + (s * 64 + o) * 64 + c0;
    unsigned int p0 = __builtin_amdgcn_cvt_pk_fp8_f32(src[0], src[1], 0, false);
    p0 = __builtin_amdgcn_cvt_pk_fp8_f32(src[2], src[3], p0, true);
    unsigned int p1 = __builtin_amdgcn_cvt_pk_fp8_f32(src[4], src[5], 0, false);
    p1 = __builtin_amdgcn_cvt_pk_fp8_f32(src[6], src[7], p1, true);
    *(uint2*)(w3f + (grp * 64 + lane) * 8) = make_uint2(p0, p1);
}

// ---- k_prep: one pass over x -> per-tc xbar partials (plain stores) + fp8 xT ----
__launch_bounds__(512)
__global__ void k_prep(const float* __restrict__ x, float* __restrict__ xbarp,
                       unsigned char* __restrict__ xT) {
    __shared__ unsigned short xl[64 * 404];   // bf16, 51,712 B -> 3 blocks/CU
    int bid = blockIdx.x;                     // 0..1023
    int n = bid >> 3, tc = bid & 7;
    int tid = threadIdx.x;                    // 512
    const float* xs = x + (size_t)n * 204800 + tc * 400;
    for (int idx = tid; idx < 6400; idx += 512) {
        int c = idx / 100, r4 = idx - c * 100;
        float4 q = *(const float4*)(xs + c * 3200 + r4 * 4);
        unsigned int lo = (unsigned int)f2bf(q.x) | ((unsigned int)f2bf(q.y) << 16);
        unsigned int hi = (unsigned int)f2bf(q.z) | ((unsigned int)f2bf(q.w) << 16);
        *(uint2*)(xl + c * 404 + r4 * 4) = make_uint2(lo, hi);
    }
    __syncthreads();
    for (int i = tid; i < 1600; i += 512) {
        int c = i / 25, v = i - c * 25;
        float ssum = 0.f;
#pragma unroll
        for (int t = 0; t < 16; t++) {
            unsigned int b = xl[c * 404 + t * 25 + v];
            union { unsigned int u; float f; } cv; cv.u = b << 16;
            ssum += cv.f;
        }
        xbarp[((size_t)tc * 128 + n) * 1600 + i] = ssum * (1.f / 128.f);
    }
    unsigned int* out = (unsigned int*)(xT) + (size_t)n * 51200 + tc * 6400;
    for (int j = tid; j < 6400; j += 512) {
        int cq = j & 15, tv = j >> 4;
        float f[4];
#pragma unroll
        for (int e = 0; e < 4; e++) {
            unsigned int b = xl[(4 * cq + e) * 404 + tv];
            union { unsigned int u; float g; } cv; cv.u = b << 16;
            f[e] = cv.g;
        }
        unsigned int pk = __builtin_amdgcn_cvt_pk_fp8_f32(f[0], f[1], 0, false);
        pk = __builtin_amdgcn_cvt_pk_fp8_f32(f[2], f[3], pk, true);
        out[j] = pk;
    }
}

// ---- K2: adj in B-fragment-linear fp8 (512 thr; each half-block does 32 o's) ----
__launch_bounds__(512)
__global__ void k_adj(const float* __restrict__ xbarp,
                      const float* __restrict__ W1, const float* __restrict__ b1,
                      const float* __restrict__ W2, const float* __restrict__ b2,
                      const float* __restrict__ W4, const float* __restrict__ b4,
                      const float* __restrict__ PA, const float* __restrict__ alpha,
                      unsigned char* __restrict__ adjf) {
    int sb = blockIdx.x;          // 0..383
    int s = sb >> 7, n = sb & 127;
    __shared__ float xb[1600], w1l[512], w2l[512], w4l[512], b4l[64], pal[625];
    __shared__ float x1l[200], x2l[200];
    __shared__ float dt[8][25][28];
    int tid = threadIdx.x;        // 512
    for (int i = tid; i < 1600; i += 512) {
        float a = 0.f;
#pragma unroll
        for (int tc = 0; tc < 8; tc++) a += xbarp[((size_t)tc * 128 + n) * 1600 + i];
        xb[i] = a;
    }
    for (int i = tid; i < 512; i += 512) {
        w1l[i] = W1[s * 512 + i];
        w2l[i] = W2[s * 512 + i];
        w4l[i] = W4[s * 512 + i];
    }
    if (tid < 64) b4l[tid] = b4[s * 64 + tid];
    for (int i = tid; i < 625; i += 512) pal[i] = PA[s * 625 + i];
    __syncthreads();
    if (tid < 200) {
        int r = tid / 25, v = tid % 25;
        float a1 = b1[s * 8 + r], a2 = b2[s * 8 + r];
        for (int c = 0; c < 64; c++) {
            float xv = xb[c * 25 + v];
            a1 += w1l[r * 64 + c] * xv;
            a2 += w2l[r * 64 + c] * xv;
        }
        x1l[tid] = a1;
        x2l[tid] = a2;
    }
    __syncthreads();
    for (int i = tid; i < 5000; i += 512) {
        int r = i / 625, uv = i % 625, u = uv / 25, v = uv % 25;
        dt[r][u][v] = tanhf(x1l[r * 25 + u] - x2l[r * 25 + v]);
    }
    for (int i = tid; i < 600; i += 512) {
        int r = i / 75, rem = i % 75, u = rem / 3, v = 25 + rem % 3;
        dt[r][u][v] = 0.f;
    }
    __syncthreads();

    int tq = tid >> 8;               // 0/1 -> o half
    int f = (tid & 255) * 4;         // byte offset within the 1024-B o-row
    int lane = (f >> 3) & 63;
    int j0 = f & 7;
    int u = ((f >> 9) << 4) + (lane & 15);
    int v0 = ((lane >> 4) << 3) + j0;
    bool uok = (u < 25);
    float4 dr[8];
    if (uok && v0 < 28) {
#pragma unroll
        for (int r = 0; r < 8; r++) dr[r] = *(const float4*)&dt[r][u][v0];
    } else {
#pragma unroll
        for (int r = 0; r < 8; r++) { dr[r].x = dr[r].y = dr[r].z = dr[r].w = 0.f; }
    }
    float al = alpha[s];
    bool vok[4]; float pae[4];
#pragma unroll
    for (int e = 0; e < 4; e++) {
        int v = v0 + e;
        vok[e] = uok && (v < 25);
        pae[e] = vok[e] ? pal[u * 25 + v] : 0.f;
    }
    unsigned char* outp = adjf + ((size_t)(s * 128 + n)) * 65536 + f;
    int o0 = tq * 32;
    for (int o = o0; o < o0 + 32; o++) {
        float b4o = b4l[o];
        float acc[4];
#pragma unroll
        for (int e = 0; e < 4; e++) {
            acc[e] = 0.f;
            if (vok[e]) {
                float dot = b4o;
#pragma unroll
                for (int r = 0; r < 8; r++) {
                    float dv = (e == 0) ? dr[r].x : (e == 1) ? dr[r].y : (e == 2) ? dr[r].z : dr[r].w;
                    dot += w4l[o * 8 + r] * dv;
                }
                acc[e] = dot * al + pae[e];
            }
        }
        unsigned int pk = __builtin_amdgcn_cvt_pk_fp8_f32(acc[0], acc[1], 0, false);
        pk = __builtin_amdgcn_cvt_pk_fp8_f32(acc[2], acc[3], pk, true);
        *(unsigned int*)(outp + o * 1024) = pk;
    }
}

// ---- K3: fp8 MFMA main (r12 schedule) + setprio around MFMA clusters ----
#define LOADAF(D0, D1, TC) do {                                                          \
    _Pragma("unroll")                                                                    \
    for (int i_ = 0; i_ < 4; i_++) {                                                     \
        int mf_ = w + 8 * i_;                                                            \
        int tvk_ = (mf_ >> 1) * 25 + vc;                                                 \
        const unsigned char* pp_ = xTn + (size_t)((TC) * 400 + tvk_) * 64 + l4 * 8;      \
        i64 a0_ = *(const i64*)pp_;                                                      \
        i64 a1_ = *(const i64*)(pp_ + 32);                                               \
        D0[i_] = vok ? a0_ : 0;                                                          \
        D1[i_] = vok ? a1_ : 0;                                                          \
    } } while (0)

#define STAGE1(S, BUF, AF0, AF1) do {                                                    \
    float bias_ = biasreg[S];                                                            \
    __builtin_amdgcn_s_setprio(1);                                                       \
    _Pragma("unroll")                                                                    \
    for (int i_ = 0; i_ < 4; i_++) {                                                     \
        f32x4 d_ = __builtin_amdgcn_mfma_f32_16x16x32_fp8_fp8(AF0[i_], bwreg[2 * (S)], zero4, 0, 0, 0); \
        d_ = __builtin_amdgcn_mfma_f32_16x16x32_fp8_fp8(AF1[i_], bwreg[2 * (S) + 1], d_, 0, 0, 0); \
        int mf_ = w + 8 * i_;                                                            \
        unsigned int pk_ = __builtin_amdgcn_cvt_pk_fp8_f32(d_[0] + bias_, d_[1] + bias_, 0, false); \
        pk_ = __builtin_amdgcn_cvt_pk_fp8_f32(d_[2] + bias_, d_[3] + bias_, pk_, true);  \
        *(unsigned int*)(x3l[BUF] + l15 * 648 + (mf_ >> 1) * 40 + ((mf_ & 1) << 4) + l4 * 4) = pk_; \
    }                                                                                    \
    __builtin_amdgcn_s_setprio(0);                                                       \
    } while (0)

#define STAGE2(S, BUF) do {                                                              \
    __builtin_amdgcn_s_setprio(1);                                                       \
    _Pragma("unroll")                                                                    \
    for (int oj_ = 0; oj_ < 2; oj_++) {                                                  \
        i64 a_ = *(const i64*)(x3l[BUF] + (2 * w + oj_) * 648 + l15 * 40 + l4 * 8);      \
        yacc[oj_ * 2 + 0] = __builtin_amdgcn_mfma_f32_16x16x32_fp8_fp8(a_, badj[(S) * 4 + oj_ * 2 + 0], yacc[oj_ * 2 + 0], 0, 0, 0); \
        yacc[oj_ * 2 + 1] = __builtin_amdgcn_mfma_f32_16x16x32_fp8_fp8(a_, badj[(S) * 4 + oj_ * 2 + 1], yacc[oj_ * 2 + 1], 0, 0, 0); \
    }                                                                                    \
    __builtin_amdgcn_s_setprio(0);                                                       \
    } while (0)

#define CHUNK(TC, AC0, AC1, AN0, AN1, P) do {                                            \
    f32x4 yacc[4] = {zero4, zero4, zero4, zero4};                                        \
    STAGE1(0, P, AC0, AC1);                                                              \
    __syncthreads();                                                                     \
    STAGE1(1, (P) ^ 1, AC0, AC1);                                                        \
    STAGE2(0, P);                                                                        \
    __syncthreads();                                                                     \
    STAGE1(2, P, AC0, AC1);                                                              \
    STAGE2(1, (P) ^ 1);                                                                  \
    if ((TC) < 7) LOADAF(AN0, AN1, (TC) + 1);                                            \
    __syncthreads();                                                                     \
    STAGE2(2, P);                                                                        \
    /* epilogue: stats + fp8 y repack (ylds wave-private; same-wave LDS RAW -> */        \
    /* compiler inserts the precise lgkmcnt, no manual full drain) */                    \
    _Pragma("unroll")                                                                    \
    for (int oj = 0; oj < 2; oj++) {                                                     \
        _Pragma("unroll")                                                                \
        for (int ut = 0; ut < 2; ut++) {                                                 \
            f32x4 d = yacc[oj * 2 + ut];                                                 \
            int u = ut * 16 + l15;                                                       \
            s1[oj] += d[0] + d[1] + d[2] + d[3];                                         \
            s2[oj] += d[0] * d[0] + d[1] * d[1] + d[2] * d[2] + d[3] * d[3];             \
            if (u < 25) {                                                                \
                _Pragma("unroll")                                                        \
                for (int r = 0; r < 4; r++) {                                            \
                    unsigned int b = __builtin_amdgcn_cvt_pk_fp8_f32(d[r], d[r], 0, false) & 0xFFu; \
                    ylds[w][oj * 400 + (l4 * 4 + r) * 25 + u] = (unsigned char)b;        \
                }                                                                        \
            }                                                                            \
        }                                                                                \
    }                                                                                    \
    _Pragma("unroll")                                                                    \
    for (int rep = 0; rep < 4; rep++) {                                                  \
        int idx = lane + rep * 64;                                                       \
        if (idx < 200) {                                                                 \
            int oj = idx >= 100 ? 1 : 0;                                                 \
            size_t gb = ((size_t)(n * 64 + oa + oj) * 3200) + (TC) * 400 + (idx - oj * 100) * 4; \
            *(unsigned int*)(y8 + gb) = *(const unsigned int*)(&ylds[w][idx * 4]);       \
        }                                                                                \
    } } while (0)

__launch_bounds__(512, 2)
__global__ void k_main(const unsigned char* __restrict__ xT, const float* __restrict__ b3g,
                       const unsigned char* __restrict__ w3f,
                       const unsigned char* __restrict__ adjf,
                       unsigned char* __restrict__ y8, float* __restrict__ partials) {
    __shared__ unsigned char x3l[2][16 * 648];    // 20,736 B, byte-stride 648 (bank-clean)
    __shared__ unsigned char ylds[8][800];        // per-wave y repack, 6,400 B

    int bid = blockIdx.x;                          // 0..511; bid&7 = n&7 -> XCD locality
    int n = bid & 127, ot = bid >> 7;
    int tid = threadIdx.x;
    int w = tid >> 6, lane = tid & 63, l15 = lane & 15, l4 = lane >> 4;
    int oa = ot * 16 + 2 * w;

    // hoisted w3 B-frags + bias (register-resident for all 8 chunks)
    i64 bwreg[6];
    float biasreg[3];
#pragma unroll
    for (int s = 0; s < 3; s++) {
        bwreg[2 * s]     = *(const i64*)(w3f + ((s * 8 + ot) * 64 + lane) * 8);
        bwreg[2 * s + 1] = *(const i64*)(w3f + ((s * 8 + 4 + ot) * 64 + lane) * 8);
        biasreg[s] = b3g[s * 64 + ot * 16 + l15];
    }

    // 12 register-resident adj B-frags (fp8, 24 VGPR): [s][oj][ut]
    i64 badj[12];
    {
        const unsigned char* ap = adjf + (size_t)n * 65536 + (size_t)oa * 1024 + lane * 8;
#pragma unroll
        for (int s = 0; s < 3; s++)
#pragma unroll
            for (int oj = 0; oj < 2; oj++)
#pragma unroll
                for (int ut = 0; ut < 2; ut++)
                    badj[s * 4 + oj * 2 + ut] =
                        *(const i64*)(ap + (size_t)s * 8388608 + oj * 1024 + ut * 512);
    }

    f32x4 zero4 = {0.f, 0.f, 0.f, 0.f};
    float s1[2] = {0.f, 0.f}, s2[2] = {0.f, 0.f};
    const unsigned char* xTn = xT + (size_t)n * 204800;
    int vrow = ((w & 1) << 4) + l15;
    bool vok = vrow < 25;
    int vc = vok ? vrow : 24;

    i64 afA0[4], afA1[4], afB0[4], afB1[4];
    LOADAF(afA0, afA1, 0);

    CHUNK(0, afA0, afA1, afB0, afB1, 0);
    CHUNK(1, afB0, afB1, afA0, afA1, 1);
    CHUNK(2, afA0, afA1, afB0, afB1, 0);
    CHUNK(3, afB0, afB1, afA0, afA1, 1);
    CHUNK(4, afA0, afA1, afB0, afB1, 0);
    CHUNK(5, afB0, afB1, afA0, afA1, 1);
    CHUNK(6, afA0, afA1, afB0, afB1, 0);
    CHUNK(7, afB0, afB1, afA0, afA1, 1);

    // deterministic per-(o,n) partials
#pragma unroll
    for (int oj = 0; oj < 2; oj++) {
        float a = s1[oj], b = s2[oj];
#pragma unroll
        for (int off = 1; off < 64; off <<= 1) {
            a += __shfl_xor(a, off);
            b += __shfl_xor(b, off);
        }
        if (lane == 0) {
            partials[((oa + oj) * 2 + 0) * 128 + n] = a;
            partials[((oa + oj) * 2 + 1) * 128 + n] = b;
        }
    }
}

// ---- fused reduce + coef ----
__global__ void k_redcoef(const float* __restrict__ partials, const float* __restrict__ bnw,
                          const float* __restrict__ bnb, float* __restrict__ coef) {
    __shared__ float st[128];
    int tid = threadIdx.x;                   // 128
    const float4* p = (const float4*)(partials + tid * 128);
    float a = 0.f;
#pragma unroll
    for (int i = 0; i < 32; i++) {
        float4 q = p[i];
        a += q.x + q.y + q.z + q.w;
    }
    st[tid] = a;
    __syncthreads();
    if (tid < 64) {
        const float inv = 1.f / 409600.f;
        float mean = st[2 * tid] * inv;
        float var = st[2 * tid + 1] * inv - mean * mean;
        float sc = bnw[tid] * rsqrtf(var + 1e-5f);
        coef[2 * tid] = sc;
        coef[2 * tid + 1] = bnb[tid] - mean * sc;
    }
}

// ---- K5: out = relu(fp8(y)*scale + shift + x) ----
__launch_bounds__(512)
__global__ void k_final(float* __restrict__ outp, const unsigned char* __restrict__ y8,
                        const float* __restrict__ x, const float* __restrict__ coef) {
    unsigned int i = blockIdx.x * 512u + threadIdx.x;   // 6,553,600 quads
    unsigned int o = (i / 800u) & 63u;
    float sc = coef[o * 2], sh = coef[o * 2 + 1];
    unsigned int yw = ((const unsigned int*)y8)[i];
    f32x2 lo = __builtin_amdgcn_cvt_pk_f32_fp8(yw, false);
    f32x2 hi = __builtin_amdgcn_cvt_pk_f32_fp8(yw, true);
    float4 xv = ((const float4*)x)[i];
    float4 r;
    r.x = fmaxf(lo[0] * sc + sh + xv.x, 0.f);
    r.y = fmaxf(lo[1] * sc + sh + xv.y, 0.f);
    r.z = fmaxf(hi[0] * sc + sh + xv.z, 0.f);
    r.w = fmaxf(hi[1] * sc + sh + xv.w, 0.f);
    ((float4*)outp)[i] = r;
}

extern "C" void kernel_launch(void* const* d_in, const int* in_sizes, int n_in,
                              void* d_out, int out_size, void* d_ws, size_t ws_size,
                              hipStream_t stream) {
    const float* x    = (const float*)d_in[0];
    const float* W1   = (const float*)d_in[1];
    const float* b1   = (const float*)d_in[2];
    const float* W2   = (const float*)d_in[3];
    const float* b2   = (const float*)d_in[4];
    const float* W3   = (const float*)d_in[5];
    const float* b3   = (const float*)d_in[6];
    const float* W4   = (const float*)d_in[7];
    const float* b4   = (const float*)d_in[8];
    const float* PA   = (const float*)d_in[9];
    const float* alpha= (const float*)d_in[10];
    const float* bnw  = (const float*)d_in[11];
    const float* bnb  = (const float*)d_in[12];

    char* wsb = (char*)d_ws;
    unsigned char* adjf  = (unsigned char*)(wsb + ADJ8_OFF);
    unsigned char* w3f   = (unsigned char*)(wsb + W3F8_OFF);
    unsigned char* xT    = (unsigned char*)(wsb + XT8_OFF);
    unsigned char* y8    = (unsigned char*)(wsb + Y8_OFF);
    float* xbarp    = (float*)(wsb + XBARP_OFF);
    float* partials = (float*)(wsb + PART_OFF);
    float* coef     = (float*)(wsb + COEF_OFF);
    float* outp     = (float*)d_out;

    hipLaunchKernelGGL(k_w3prep, dim3(3), dim3(512), 0, stream, W3, w3f);
    hipLaunchKernelGGL(k_prep, dim3(1024), dim3(512), 0, stream, x, xbarp, xT);
    hipLaunchKernelGGL(k_adj, dim3(384), dim3(512), 0, stream,
                       xbarp, W1, b1, W2, b2, W4, b4, PA, alpha, adjf);
    hipLaunchKernelGGL(k_main, dim3(512), dim3(512), 0, stream,
                       xT, b3, w3f, adjf, y8, partials);
    hipLaunchKernelGGL(k_redcoef, dim3(1), dim3(128), 0, stream, partials, bnw, bnb, coef);
    hipLaunchKernelGGL(k_final, dim3(12800), dim3(512), 0, stream, outp, y8, x, coef);
}

// Round 16
// 138.319 us; speedup vs baseline: 1.0363x; 1.0363x over previous
//
#include <hip/hip_runtime.h>
#include <hip/hip_bf16.h>

// Shapes: N=128, C_IN=C_OUT=64, T=128, V=25, S=3, R=8
// ws layout (bytes) — all matrices fp8 e4m3:
//   adjfrag [3][128][64 o][2 ut][64 lane][8 j]   @ 0           25,165,824
//   w3frag  [3][2 kb][4 ot][64 lane][8 j]        @ 25,165,824      12,288
//   xT      [128][3200 tv][64 c]                 @ 25,178,112  26,214,400
//   y8      [128][64][128 t][25 u]               @ 51,392,512  26,214,400
//   xbarp f32 [8 tc][128 n][1600]                @ 77,606,912   6,553,600
//   partials f32 [64 o][2 stat][128 n]           @ 84,160,512      65,536
//   coef f32 [64][2]                             @ 84,226,048         512
//
// NOTE (toolchain, r8/r9): __launch_bounds__ 2nd arg acts as min BLOCKS/CU on
// this hipcc: (512,4)->64 VGPR cap, (512,6)->40, (512,2)->128.
// NOTE (r11): hipLaunchCooperativeKernel breaks under graph capture — avoid.
// NOTE (r12-r15): k_main is dependency-latency-bound and schedule-invariant:
// 3-barrier (r12, 138.9us) == 1-barrier pipeline (r13) == store-free (r14);
// setprio/no-drain slightly negative (r15). This file is r12 verbatim (best).

typedef __attribute__((ext_vector_type(4))) float f32x4;
typedef __attribute__((ext_vector_type(2))) float f32x2;
typedef long long i64;

#define ADJ8_OFF  0
#define W3F8_OFF  25165824
#define XT8_OFF   25178112
#define Y8_OFF    51392512
#define XBARP_OFF 77606912
#define PART_OFF  84160512
#define COEF_OFF  84226048

__device__ inline unsigned short f2bf(float f) {
    union { float f; unsigned int u; } x; x.f = f;
    unsigned int u = x.u;
    return (unsigned short)((u + 0x7FFFu + ((u >> 16) & 1u)) >> 16);
}

// ---- W3 -> B-fragment-linear fp8 ----
__global__ void k_w3prep(const float* __restrict__ W3, unsigned char* __restrict__ w3f) {
    int g = blockIdx.x * 512 + threadIdx.x;          // 0..1535
    if (g >= 1536) return;
    int grp = g >> 6, lane = g & 63;
    int s = grp >> 3, kb = (grp >> 2) & 1, ot = grp & 3;
    int o = ot * 16 + (lane & 15);
    int c0 = kb * 32 + (lane >> 4) * 8;
    const float* src = W3 + (s * 64 + o) * 64 + c0;
    unsigned int p0 = __builtin_amdgcn_cvt_pk_fp8_f32(src[0], src[1], 0, false);
    p0 = __builtin_amdgcn_cvt_pk_fp8_f32(src[2], src[3], p0, true);
    unsigned int p1 = __builtin_amdgcn_cvt_pk_fp8_f32(src[4], src[5], 0, false);
    p1 = __builtin_amdgcn_cvt_pk_fp8_f32(src[6], src[7], p1, true);
    *(uint2*)(w3f + (grp * 64 + lane) * 8) = make_uint2(p0, p1);
}

// ---- k_prep: one pass over x -> per-tc xbar partials (plain stores) + fp8 xT ----
__launch_bounds__(512)
__global__ void k_prep(const float* __restrict__ x, float* __restrict__ xbarp,
                       unsigned char* __restrict__ xT) {
    __shared__ unsigned short xl[64 * 404];   // bf16, 51,712 B -> 3 blocks/CU
    int bid = blockIdx.x;                     // 0..1023
    int n = bid >> 3, tc = bid & 7;
    int tid = threadIdx.x;                    // 512
    const float* xs = x + (size_t)n * 204800 + tc * 400;
    for (int idx = tid; idx < 6400; idx += 512) {
        int c = idx / 100, r4 = idx - c * 100;
        float4 q = *(const float4*)(xs + c * 3200 + r4 * 4);
        unsigned int lo = (unsigned int)f2bf(q.x) | ((unsigned int)f2bf(q.y) << 16);
        unsigned int hi = (unsigned int)f2bf(q.z) | ((unsigned int)f2bf(q.w) << 16);
        *(uint2*)(xl + c * 404 + r4 * 4) = make_uint2(lo, hi);
    }
    __syncthreads();
    for (int i = tid; i < 1600; i += 512) {
        int c = i / 25, v = i - c * 25;
        float ssum = 0.f;
#pragma unroll
        for (int t = 0; t < 16; t++) {
            unsigned int b = xl[c * 404 + t * 25 + v];
            union { unsigned int u; float f; } cv; cv.u = b << 16;
            ssum += cv.f;
        }
        xbarp[((size_t)tc * 128 + n) * 1600 + i] = ssum * (1.f / 128.f);
    }
    unsigned int* out = (unsigned int*)(xT) + (size_t)n * 51200 + tc * 6400;
    for (int j = tid; j < 6400; j += 512) {
        int cq = j & 15, tv = j >> 4;
        float f[4];
#pragma unroll
        for (int e = 0; e < 4; e++) {
            unsigned int b = xl[(4 * cq + e) * 404 + tv];
            union { unsigned int u; float g; } cv; cv.u = b << 16;
            f[e] = cv.g;
        }
        unsigned int pk = __builtin_amdgcn_cvt_pk_fp8_f32(f[0], f[1], 0, false);
        pk = __builtin_amdgcn_cvt_pk_fp8_f32(f[2], f[3], pk, true);
        out[j] = pk;
    }
}

// ---- K2: adj in B-fragment-linear fp8 (512 thr; each half-block does 32 o's) ----
__launch_bounds__(512)
__global__ void k_adj(const float* __restrict__ xbarp,
                      const float* __restrict__ W1, const float* __restrict__ b1,
                      const float* __restrict__ W2, const float* __restrict__ b2,
                      const float* __restrict__ W4, const float* __restrict__ b4,
                      const float* __restrict__ PA, const float* __restrict__ alpha,
                      unsigned char* __restrict__ adjf) {
    int sb = blockIdx.x;          // 0..383
    int s = sb >> 7, n = sb & 127;
    __shared__ float xb[1600], w1l[512], w2l[512], w4l[512], b4l[64], pal[625];
    __shared__ float x1l[200], x2l[200];
    __shared__ float dt[8][25][28];
    int tid = threadIdx.x;        // 512
    for (int i = tid; i < 1600; i += 512) {
        float a = 0.f;
#pragma unroll
        for (int tc = 0; tc < 8; tc++) a += xbarp[((size_t)tc * 128 + n) * 1600 + i];
        xb[i] = a;
    }
    for (int i = tid; i < 512; i += 512) {
        w1l[i] = W1[s * 512 + i];
        w2l[i] = W2[s * 512 + i];
        w4l[i] = W4[s * 512 + i];
    }
    if (tid < 64) b4l[tid] = b4[s * 64 + tid];
    for (int i = tid; i < 625; i += 512) pal[i] = PA[s * 625 + i];
    __syncthreads();
    if (tid < 200) {
        int r = tid / 25, v = tid % 25;
        float a1 = b1[s * 8 + r], a2 = b2[s * 8 + r];
        for (int c = 0; c < 64; c++) {
            float xv = xb[c * 25 + v];
            a1 += w1l[r * 64 + c] * xv;
            a2 += w2l[r * 64 + c] * xv;
        }
        x1l[tid] = a1;
        x2l[tid] = a2;
    }
    __syncthreads();
    for (int i = tid; i < 5000; i += 512) {
        int r = i / 625, uv = i % 625, u = uv / 25, v = uv % 25;
        dt[r][u][v] = tanhf(x1l[r * 25 + u] - x2l[r * 25 + v]);
    }
    for (int i = tid; i < 600; i += 512) {
        int r = i / 75, rem = i % 75, u = rem / 3, v = 25 + rem % 3;
        dt[r][u][v] = 0.f;
    }
    __syncthreads();

    int tq = tid >> 8;               // 0/1 -> o half
    int f = (tid & 255) * 4;         // byte offset within the 1024-B o-row
    int lane = (f >> 3) & 63;
    int j0 = f & 7;
    int u = ((f >> 9) << 4) + (lane & 15);
    int v0 = ((lane >> 4) << 3) + j0;
    bool uok = (u < 25);
    float4 dr[8];
    if (uok && v0 < 28) {
#pragma unroll
        for (int r = 0; r < 8; r++) dr[r] = *(const float4*)&dt[r][u][v0];
    } else {
#pragma unroll
        for (int r = 0; r < 8; r++) { dr[r].x = dr[r].y = dr[r].z = dr[r].w = 0.f; }
    }
    float al = alpha[s];
    bool vok[4]; float pae[4];
#pragma unroll
    for (int e = 0; e < 4; e++) {
        int v = v0 + e;
        vok[e] = uok && (v < 25);
        pae[e] = vok[e] ? pal[u * 25 + v] : 0.f;
    }
    unsigned char* outp = adjf + ((size_t)(s * 128 + n)) * 65536 + f;
    int o0 = tq * 32;
    for (int o = o0; o < o0 + 32; o++) {
        float b4o = b4l[o];
        float acc[4];
#pragma unroll
        for (int e = 0; e < 4; e++) {
            acc[e] = 0.f;
            if (vok[e]) {
                float dot = b4o;
#pragma unroll
                for (int r = 0; r < 8; r++) {
                    float dv = (e == 0) ? dr[r].x : (e == 1) ? dr[r].y : (e == 2) ? dr[r].z : dr[r].w;
                    dot += w4l[o * 8 + r] * dv;
                }
                acc[e] = dot * al + pae[e];
            }
        }
        unsigned int pk = __builtin_amdgcn_cvt_pk_fp8_f32(acc[0], acc[1], 0, false);
        pk = __builtin_amdgcn_cvt_pk_fp8_f32(acc[2], acc[3], pk, true);
        *(unsigned int*)(outp + o * 1024) = pk;
    }
}

// ---- K3: fp8 MFMA main. grid 512 = (n, 16-o tile). 3 barriers/chunk (parity x3l),
//      A-frag global loads double-buffered in registers (issue-early),
//      w3 B-frags + bias hoisted to registers for the whole t-loop.
#define LOADAF(D0, D1, TC) do {                                                          \
    _Pragma("unroll")                                                                    \
    for (int i_ = 0; i_ < 4; i_++) {                                                     \
        int mf_ = w + 8 * i_;                                                            \
        int tvk_ = (mf_ >> 1) * 25 + vc;                                                 \
        const unsigned char* pp_ = xTn + (size_t)((TC) * 400 + tvk_) * 64 + l4 * 8;      \
        i64 a0_ = *(const i64*)pp_;                                                      \
        i64 a1_ = *(const i64*)(pp_ + 32);                                               \
        D0[i_] = vok ? a0_ : 0;                                                          \
        D1[i_] = vok ? a1_ : 0;                                                          \
    } } while (0)

#define STAGE1(S, BUF, AF0, AF1) do {                                                    \
    float bias_ = biasreg[S];                                                            \
    _Pragma("unroll")                                                                    \
    for (int i_ = 0; i_ < 4; i_++) {                                                     \
        f32x4 d_ = __builtin_amdgcn_mfma_f32_16x16x32_fp8_fp8(AF0[i_], bwreg[2 * (S)], zero4, 0, 0, 0); \
        d_ = __builtin_amdgcn_mfma_f32_16x16x32_fp8_fp8(AF1[i_], bwreg[2 * (S) + 1], d_, 0, 0, 0); \
        int mf_ = w + 8 * i_;                                                            \
        unsigned int pk_ = __builtin_amdgcn_cvt_pk_fp8_f32(d_[0] + bias_, d_[1] + bias_, 0, false); \
        pk_ = __builtin_amdgcn_cvt_pk_fp8_f32(d_[2] + bias_, d_[3] + bias_, pk_, true);  \
        *(unsigned int*)(x3l[BUF] + l15 * 648 + (mf_ >> 1) * 40 + ((mf_ & 1) << 4) + l4 * 4) = pk_; \
    } } while (0)

#define STAGE2(S, BUF) do {                                                              \
    _Pragma("unroll")                                                                    \
    for (int oj_ = 0; oj_ < 2; oj_++) {                                                  \
        i64 a_ = *(const i64*)(x3l[BUF] + (2 * w + oj_) * 648 + l15 * 40 + l4 * 8);      \
        yacc[oj_ * 2 + 0] = __builtin_amdgcn_mfma_f32_16x16x32_fp8_fp8(a_, badj[(S) * 4 + oj_ * 2 + 0], yacc[oj_ * 2 + 0], 0, 0, 0); \
        yacc[oj_ * 2 + 1] = __builtin_amdgcn_mfma_f32_16x16x32_fp8_fp8(a_, badj[(S) * 4 + oj_ * 2 + 1], yacc[oj_ * 2 + 1], 0, 0, 0); \
    } } while (0)

#define CHUNK(TC, AC0, AC1, AN0, AN1, P) do {                                            \
    f32x4 yacc[4] = {zero4, zero4, zero4, zero4};                                        \
    STAGE1(0, P, AC0, AC1);                                                              \
    __syncthreads();                                                                     \
    STAGE1(1, (P) ^ 1, AC0, AC1);                                                        \
    STAGE2(0, P);                                                                        \
    __syncthreads();                                                                     \
    STAGE1(2, P, AC0, AC1);                                                              \
    STAGE2(1, (P) ^ 1);                                                                  \
    if ((TC) < 7) LOADAF(AN0, AN1, (TC) + 1);                                            \
    __syncthreads();                                                                     \
    STAGE2(2, P);                                                                        \
    /* epilogue: stats + fp8 y repack (ylds wave-private; parity covers x3l reuse) */    \
    _Pragma("unroll")                                                                    \
    for (int oj = 0; oj < 2; oj++) {                                                     \
        _Pragma("unroll")                                                                \
        for (int ut = 0; ut < 2; ut++) {                                                 \
            f32x4 d = yacc[oj * 2 + ut];                                                 \
            int u = ut * 16 + l15;                                                       \
            s1[oj] += d[0] + d[1] + d[2] + d[3];                                         \
            s2[oj] += d[0] * d[0] + d[1] * d[1] + d[2] * d[2] + d[3] * d[3];             \
            if (u < 25) {                                                                \
                _Pragma("unroll")                                                        \
                for (int r = 0; r < 4; r++) {                                            \
                    unsigned int b = __builtin_amdgcn_cvt_pk_fp8_f32(d[r], d[r], 0, false) & 0xFFu; \
                    ylds[w][oj * 400 + (l4 * 4 + r) * 25 + u] = (unsigned char)b;        \
                }                                                                        \
            }                                                                            \
        }                                                                                \
    }                                                                                    \
    asm volatile("s_waitcnt lgkmcnt(0)" ::: "memory");                                   \
    _Pragma("unroll")                                                                    \
    for (int rep = 0; rep < 4; rep++) {                                                  \
        int idx = lane + rep * 64;                                                       \
        if (idx < 200) {                                                                 \
            int oj = idx >= 100 ? 1 : 0;                                                 \
            size_t gb = ((size_t)(n * 64 + oa + oj) * 3200) + (TC) * 400 + (idx - oj * 100) * 4; \
            *(unsigned int*)(y8 + gb) = *(const unsigned int*)(&ylds[w][idx * 4]);       \
        }                                                                                \
    } } while (0)

__launch_bounds__(512, 2)
__global__ void k_main(const unsigned char* __restrict__ xT, const float* __restrict__ b3g,
                       const unsigned char* __restrict__ w3f,
                       const unsigned char* __restrict__ adjf,
                       unsigned char* __restrict__ y8, float* __restrict__ partials) {
    __shared__ unsigned char x3l[2][16 * 648];    // 20,736 B, byte-stride 648 (bank-clean)
    __shared__ unsigned char ylds[8][800];        // per-wave y repack, 6,400 B

    int bid = blockIdx.x;                          // 0..511; bid&7 = n&7 -> XCD locality
    int n = bid & 127, ot = bid >> 7;
    int tid = threadIdx.x;
    int w = tid >> 6, lane = tid & 63, l15 = lane & 15, l4 = lane >> 4;
    int oa = ot * 16 + 2 * w;

    // hoisted w3 B-frags + bias (register-resident for all 8 chunks)
    i64 bwreg[6];
    float biasreg[3];
#pragma unroll
    for (int s = 0; s < 3; s++) {
        bwreg[2 * s]     = *(const i64*)(w3f + ((s * 8 + ot) * 64 + lane) * 8);
        bwreg[2 * s + 1] = *(const i64*)(w3f + ((s * 8 + 4 + ot) * 64 + lane) * 8);
        biasreg[s] = b3g[s * 64 + ot * 16 + l15];
    }

    // 12 register-resident adj B-frags (fp8, 24 VGPR): [s][oj][ut]
    i64 badj[12];
    {
        const unsigned char* ap = adjf + (size_t)n * 65536 + (size_t)oa * 1024 + lane * 8;
#pragma unroll
        for (int s = 0; s < 3; s++)
#pragma unroll
            for (int oj = 0; oj < 2; oj++)
#pragma unroll
                for (int ut = 0; ut < 2; ut++)
                    badj[s * 4 + oj * 2 + ut] =
                        *(const i64*)(ap + (size_t)s * 8388608 + oj * 1024 + ut * 512);
    }

    f32x4 zero4 = {0.f, 0.f, 0.f, 0.f};
    float s1[2] = {0.f, 0.f}, s2[2] = {0.f, 0.f};
    const unsigned char* xTn = xT + (size_t)n * 204800;
    int vrow = ((w & 1) << 4) + l15;
    bool vok = vrow < 25;
    int vc = vok ? vrow : 24;

    i64 afA0[4], afA1[4], afB0[4], afB1[4];
    LOADAF(afA0, afA1, 0);

    CHUNK(0, afA0, afA1, afB0, afB1, 0);
    CHUNK(1, afB0, afB1, afA0, afA1, 1);
    CHUNK(2, afA0, afA1, afB0, afB1, 0);
    CHUNK(3, afB0, afB1, afA0, afA1, 1);
    CHUNK(4, afA0, afA1, afB0, afB1, 0);
    CHUNK(5, afB0, afB1, afA0, afA1, 1);
    CHUNK(6, afA0, afA1, afB0, afB1, 0);
    CHUNK(7, afB0, afB1, afA0, afA1, 1);

    // deterministic per-(o,n) partials
#pragma unroll
    for (int oj = 0; oj < 2; oj++) {
        float a = s1[oj], b = s2[oj];
#pragma unroll
        for (int off = 1; off < 64; off <<= 1) {
            a += __shfl_xor(a, off);
            b += __shfl_xor(b, off);
        }
        if (lane == 0) {
            partials[((oa + oj) * 2 + 0) * 128 + n] = a;
            partials[((oa + oj) * 2 + 1) * 128 + n] = b;
        }
    }
}

// ---- fused reduce + coef ----
__global__ void k_redcoef(const float* __restrict__ partials, const float* __restrict__ bnw,
                          const float* __restrict__ bnb, float* __restrict__ coef) {
    __shared__ float st[128];
    int tid = threadIdx.x;                   // 128
    const float4* p = (const float4*)(partials + tid * 128);
    float a = 0.f;
#pragma unroll
    for (int i = 0; i < 32; i++) {
        float4 q = p[i];
        a += q.x + q.y + q.z + q.w;
    }
    st[tid] = a;
    __syncthreads();
    if (tid < 64) {
        const float inv = 1.f / 409600.f;
        float mean = st[2 * tid] * inv;
        float var = st[2 * tid + 1] * inv - mean * mean;
        float sc = bnw[tid] * rsqrtf(var + 1e-5f);
        coef[2 * tid] = sc;
        coef[2 * tid + 1] = bnb[tid] - mean * sc;
    }
}

// ---- K5: out = relu(fp8(y)*scale + shift + x) ----
__launch_bounds__(512)
__global__ void k_final(float* __restrict__ outp, const unsigned char* __restrict__ y8,
                        const float* __restrict__ x, const float* __restrict__ coef) {
    unsigned int i = blockIdx.x * 512u + threadIdx.x;   // 6,553,600 quads
    unsigned int o = (i / 800u) & 63u;
    float sc = coef[o * 2], sh = coef[o * 2 + 1];
    unsigned int yw = ((const unsigned int*)y8)[i];
    f32x2 lo = __builtin_amdgcn_cvt_pk_f32_fp8(yw, false);
    f32x2 hi = __builtin_amdgcn_cvt_pk_f32_fp8(yw, true);
    float4 xv = ((const float4*)x)[i];
    float4 r;
    r.x = fmaxf(lo[0] * sc + sh + xv.x, 0.f);
    r.y = fmaxf(lo[1] * sc + sh + xv.y, 0.f);
    r.z = fmaxf(hi[0] * sc + sh + xv.z, 0.f);
    r.w = fmaxf(hi[1] * sc + sh + xv.w, 0.f);
    ((float4*)outp)[i] = r;
}

extern "C" void kernel_launch(void* const* d_in, const int* in_sizes, int n_in,
                              void* d_out, int out_size, void* d_ws, size_t ws_size,
                              hipStream_t stream) {
    const float* x    = (const float*)d_in[0];
    const float* W1   = (const float*)d_in[1];
    const float* b1   = (const float*)d_in[2];
    const float* W2   = (const float*)d_in[3];
    const float* b2   = (const float*)d_in[4];
    const float* W3   = (const float*)d_in[5];
    const float* b3   = (const float*)d_in[6];
    const float* W4   = (const float*)d_in[7];
    const float* b4   = (const float*)d_in[8];
    const float* PA   = (const float*)d_in[9];
    const float* alpha= (const float*)d_in[10];
    const float* bnw  = (const float*)d_in[11];
    const float* bnb  = (const float*)d_in[12];

    char* wsb = (char*)d_ws;
    unsigned char* adjf  = (unsigned char*)(wsb + ADJ8_OFF);
    unsigned char* w3f   = (unsigned char*)(wsb + W3F8_OFF);
    unsigned char* xT    = (unsigned char*)(wsb + XT8_OFF);
    unsigned char* y8    = (unsigned char*)(wsb + Y8_OFF);
    float* xbarp    = (float*)(wsb + XBARP_OFF);
    float* partials = (float*)(wsb + PART_OFF);
    float* coef     = (float*)(wsb + COEF_OFF);
    float* outp     = (float*)d_out;

    hipLaunchKernelGGL(k_w3prep, dim3(3), dim3(512), 0, stream, W3, w3f);
    hipLaunchKernelGGL(k_prep, dim3(1024), dim3(512), 0, stream, x, xbarp, xT);
    hipLaunchKernelGGL(k_adj, dim3(384), dim3(512), 0, stream,
                       xbarp, W1, b1, W2, b2, W4, b4, PA, alpha, adjf);
    hipLaunchKernelGGL(k_main, dim3(512), dim3(512), 0, stream,
                       xT, b3, w3f, adjf, y8, partials);
    hipLaunchKernelGGL(k_redcoef, dim3(1), dim3(128), 0, stream, partials, bnw, bnb, coef);
    hipLaunchKernelGGL(k_final, dim3(12800), dim3(512), 0, stream, outp, y8, x, coef);
}